// Round 1
// baseline (275.846 us; speedup 1.0000x reference)
//
#include <hip/hip_runtime.h>
#include <hip/hip_bf16.h>

typedef __attribute__((ext_vector_type(8))) short bf16x8;
typedef __attribute__((ext_vector_type(4))) float f32x4;
typedef unsigned short u16;

#define ATT_SCALE 0.125f

__device__ __forceinline__ u16 f2bf(float f){
  __hip_bfloat16 h = __float2bfloat16(f);
  return *reinterpret_cast<u16*>(&h);
}
__device__ __forceinline__ float bf2f(u16 u){
  __hip_bfloat16 h;
  *reinterpret_cast<u16*>(&h) = u;
  return __bfloat162float(h);
}

__global__ __launch_bounds__(256) void cvt_kernel(const float* __restrict__ src,
                                                  u16* __restrict__ dst, int n4){
  int i = blockIdx.x*256 + threadIdx.x;
  if (i < n4){
    float4 v = reinterpret_cast<const float4*>(src)[i];
    ushort4 o;
    o.x = f2bf(v.x); o.y = f2bf(v.y); o.z = f2bf(v.z); o.w = f2bf(v.w);
    reinterpret_cast<ushort4*>(dst)[i] = o;
  }
}

// C = A(MxK) * B(NxK)^T, A/B bf16 row-major, batched over blockIdx.z.
// MODE 0: QKV scatter -> Q[B,H,N,D](C0), K[B,H,N,D](C1), Vt[B,H,D,N](C2)
// MODE 1: bf16 store, batch stride sC (scores)
// MODE 2: PV -> tmp[B,N,H,D] bf16 (z = b*12+h)
// MODE 3: fp32 store + bias (projection)
template<int BM, int BN, int MODE>
__global__ __launch_bounds__(256) void gemm_bt(
    const u16* __restrict__ A, const u16* __restrict__ B,
    void* __restrict__ C0, void* __restrict__ C1, void* __restrict__ C2,
    const float* __restrict__ bias,
    int M, int N, int K, int lda, int ldb, long sA, long sB, long sC)
{
  constexpr int BK = 32, LDT = 40;   // +8 pad: 80B row stride, conflict-free-ish, 16B aligned
  __shared__ u16 As[BM*LDT];
  __shared__ u16 Bs[BN*LDT];
  const int z = blockIdx.z;
  const u16* Ab = A + (long)z * sA;
  const u16* Bb = B + (long)z * sB;
  const int bm = blockIdx.x * BM, bn = blockIdx.y * BN;
  const int tid = threadIdx.x, lane = tid & 63, wv = tid >> 6;
  constexpr int WM = BM/2, WN = BN/2, FM = WM/16, FN = WN/16;
  const int wm = (wv >> 1) * WM, wn = (wv & 1) * WN;
  const int quad = lane >> 4, cl = lane & 15;
  f32x4 acc[FM][FN];
  #pragma unroll
  for (int i=0;i<FM;i++)
    #pragma unroll
    for (int j=0;j<FN;j++){ f32x4 zr = {0.f,0.f,0.f,0.f}; acc[i][j] = zr; }
  constexpr int AIT = (BM*BK)/(8*256);
  constexpr int BIT = (BN*BK)/(8*256);

  for (int kb = 0; kb < K; kb += BK){
    __syncthreads();
    #pragma unroll
    for (int sL=0; sL<AIT; sL++){
      int e = tid + sL*256, r = e >> 2, c8 = (e & 3) * 8;
      *reinterpret_cast<float4*>(&As[r*LDT + c8]) =
        *reinterpret_cast<const float4*>(Ab + (long)(bm + r)*lda + kb + c8);
    }
    #pragma unroll
    for (int sL=0; sL<BIT; sL++){
      int e = tid + sL*256, r = e >> 2, c8 = (e & 3) * 8;
      *reinterpret_cast<float4*>(&Bs[r*LDT + c8]) =
        *reinterpret_cast<const float4*>(Bb + (long)(bn + r)*ldb + kb + c8);
    }
    __syncthreads();
    bf16x8 af[FM], bfr[FN];
    #pragma unroll
    for (int i=0;i<FM;i++)
      af[i] = *reinterpret_cast<const bf16x8*>(&As[(wm + i*16 + cl)*LDT + quad*8]);
    #pragma unroll
    for (int j=0;j<FN;j++)
      bfr[j] = *reinterpret_cast<const bf16x8*>(&Bs[(wn + j*16 + cl)*LDT + quad*8]);
    #pragma unroll
    for (int i=0;i<FM;i++)
      #pragma unroll
      for (int j=0;j<FN;j++)
        acc[i][j] = __builtin_amdgcn_mfma_f32_16x16x32_bf16(af[i], bfr[j], acc[i][j], 0, 0, 0);
  }

  #pragma unroll
  for (int i=0;i<FM;i++)
  #pragma unroll
  for (int j=0;j<FN;j++)
  #pragma unroll
  for (int r=0;r<4;r++){
    int gm = bm + wm + i*16 + quad*4 + r;
    int gn = bn + wn + j*16 + cl;
    float v = acc[i][j][r];
    if (MODE == 0){
      int b_ = gm >> 10, n_ = gm & 1023;
      int t3 = (gn >= 1536) ? 2 : ((gn >= 768) ? 1 : 0);
      int rem = gn - t3*768;
      int h = rem >> 6, d = rem & 63;
      u16 hv = f2bf(v);
      if (t3 == 0)      ((u16*)C0)[((long)((b_*12 + h)*1024 + n_))*64 + d] = hv;
      else if (t3 == 1) ((u16*)C1)[((long)((b_*12 + h)*1024 + n_))*64 + d] = hv;
      else              ((u16*)C2)[((long)((b_*12 + h)*64 + d))*1024 + n_] = hv;
    } else if (MODE == 1){
      ((u16*)C0)[(long)z*sC + (long)gm*N + gn] = f2bf(v);
    } else if (MODE == 2){
      int b_ = z / 12, h = z - b_*12;
      ((u16*)C0)[((long)((b_*1024 + gm)*12 + h))*64 + gn] = f2bf(v);
    } else {
      ((float*)C0)[(long)gm*N + gn] = v + bias[gn];
    }
  }
}

// One block per (b,n): pre-mix + softmax + post-mix over full m-row, in place on S.
__global__ __launch_bounds__(256) void mix_kernel(
    u16* __restrict__ S, const float* __restrict__ mask,
    const float* __restrict__ w_pre, const float* __restrict__ w_post)
{
  const int bid = blockIdx.x;
  const int b = bid >> 10, n = bid & 1023;
  const int t = threadIdx.x, wv = t >> 6, lane = t & 63;
  const int m0 = t * 4;

  float s[12][4];
  #pragma unroll
  for (int h=0; h<12; h++){
    ushort4 v = *reinterpret_cast<const ushort4*>(
        S + ((long)((b*12 + h)*1024 + n))*1024 + m0);
    s[h][0]=bf2f(v.x); s[h][1]=bf2f(v.y); s[h][2]=bf2f(v.z); s[h][3]=bf2f(v.w);
  }
  float4 mk = *reinterpret_cast<const float4*>(mask + ((long)(b*1024 + n))*1024 + m0);
  float mkv[4] = {mk.x, mk.y, mk.z, mk.w};

  float smix[12][4];
  #pragma unroll
  for (int g=0; g<12; g++){
    float rs = 0.f;
    #pragma unroll
    for (int h=0; h<12; h++) rs += w_pre[g*12 + h];   // uniform -> s_load
    #pragma unroll
    for (int mi=0; mi<4; mi++) smix[g][mi] = rs * mkv[mi];
    #pragma unroll
    for (int h=0; h<12; h++){
      float w = w_pre[g*12 + h] * ATT_SCALE;
      #pragma unroll
      for (int mi=0; mi<4; mi++) smix[g][mi] += w * s[h][mi];
    }
  }

  __shared__ float redA[12][4];
  __shared__ float redB[12][4];
  float Mg[12];
  #pragma unroll
  for (int g=0; g<12; g++){
    float v = fmaxf(fmaxf(smix[g][0], smix[g][1]), fmaxf(smix[g][2], smix[g][3]));
    #pragma unroll
    for (int off=32; off>0; off>>=1) v = fmaxf(v, __shfl_xor(v, off));
    if (lane == 0) redA[g][wv] = v;
  }
  __syncthreads();
  #pragma unroll
  for (int g=0; g<12; g++)
    Mg[g] = fmaxf(fmaxf(redA[g][0], redA[g][1]), fmaxf(redA[g][2], redA[g][3]));

  #pragma unroll
  for (int g=0; g<12; g++){
    float sum = 0.f;
    #pragma unroll
    for (int mi=0; mi<4; mi++){
      float e = __expf(smix[g][mi] - Mg[g]);
      smix[g][mi] = e; sum += e;
    }
    #pragma unroll
    for (int off=32; off>0; off>>=1) sum += __shfl_xor(sum, off);
    if (lane == 0) redB[g][wv] = sum;
  }
  __syncthreads();
  #pragma unroll
  for (int g=0; g<12; g++){
    float L = redB[g][0] + redB[g][1] + redB[g][2] + redB[g][3];
    float inv = 1.f / L;
    #pragma unroll
    for (int mi=0; mi<4; mi++) smix[g][mi] *= inv;
  }

  #pragma unroll
  for (int h=0; h<12; h++){
    float o0=0.f,o1=0.f,o2=0.f,o3=0.f;
    #pragma unroll
    for (int g=0; g<12; g++){
      float w = w_post[h*12 + g];   // uniform -> s_load
      o0 += w*smix[g][0]; o1 += w*smix[g][1]; o2 += w*smix[g][2]; o3 += w*smix[g][3];
    }
    ushort4 st; st.x=f2bf(o0); st.y=f2bf(o1); st.z=f2bf(o2); st.w=f2bf(o3);
    *reinterpret_cast<ushort4*>(S + ((long)((b*12 + h)*1024 + n))*1024 + m0) = st;
  }
}

extern "C" void kernel_launch(void* const* d_in, const int* in_sizes, int n_in,
                              void* d_out, int out_size, void* d_ws, size_t ws_size,
                              hipStream_t stream)
{
  const float* x      = (const float*)d_in[0];
  const float* mask   = (const float*)d_in[1];
  const float* w_qkv  = (const float*)d_in[2];
  const float* w_proj = (const float*)d_in[3];
  const float* b_proj = (const float*)d_in[4];
  const float* w_pre  = (const float*)d_in[5];
  const float* w_post = (const float*)d_in[6];
  float* out = (float*)d_out;

  u16* xb     = (u16*)d_ws;
  u16* wqkvb  = xb     + 4096l*768;
  u16* wprojb = wqkvb  + 2304l*768;
  u16* Qb     = wprojb + 768l*768;
  u16* Kb     = Qb     + 48l*1024*64;
  u16* Vtb    = Kb     + 48l*1024*64;
  u16* tmpb   = Vtb    + 48l*1024*64;
  u16* Sb     = tmpb   + 4096l*768;
  size_t need = ((size_t)(Sb - xb) + 48ul*1024*1024) * sizeof(u16);
  if (ws_size < need) return;   // insufficient scratch: fail visibly

  cvt_kernel<<<(4096*768/4 + 255)/256, 256, 0, stream>>>(x,      xb,     4096*768/4);
  cvt_kernel<<<(2304*768/4 + 255)/256, 256, 0, stream>>>(w_qkv,  wqkvb,  2304*768/4);
  cvt_kernel<<<(768*768/4  + 255)/256, 256, 0, stream>>>(w_proj, wprojb, 768*768/4);

  dim3 gq(4096/128, 2304/128, 1);
  gemm_bt<128,128,0><<<gq, 256, 0, stream>>>(xb, wqkvb, Qb, Kb, Vtb, nullptr,
      4096, 2304, 768, 768, 768, 0, 0, 0);

  dim3 gs(1024/128, 1024/128, 48);
  gemm_bt<128,128,1><<<gs, 256, 0, stream>>>(Qb, Kb, Sb, nullptr, nullptr, nullptr,
      1024, 1024, 64, 64, 64, 1024l*64, 1024l*64, 1024l*1024);

  mix_kernel<<<4096, 256, 0, stream>>>(Sb, mask, w_pre, w_post);

  dim3 gp(1024/128, 1, 48);
  gemm_bt<128,64,2><<<gp, 256, 0, stream>>>(Sb, Vtb, tmpb, nullptr, nullptr, nullptr,
      1024, 64, 1024, 1024, 1024, 1024l*1024, 64l*1024, 0);

  dim3 go(4096/128, 768/128, 1);
  gemm_bt<128,128,3><<<go, 256, 0, stream>>>(tmpb, wprojb, out, nullptr, nullptr, b_proj,
      4096, 768, 768, 768, 768, 0, 0, 0);
}